// Round 2
// baseline (356.903 us; speedup 1.0000x reference)
//
#include <hip/hip_runtime.h>

// AgreementRouting: capsule dynamic routing, split into per-iteration
// {pass, squash} kernels so S can be partitioned across many blocks.
// Identity used: b_r = b_param + dot(u, sum_{j<r} v_j)  (dot is linear in v),
// so no logit tensor is materialized anywhere -- only vcum[B,G,O,D].
// Shapes fixed: u[B=32][G=8][S=1152][O=10][D=16] f32, b_param[G][1][S][O] f32.
#define NB 32
#define NG 8
#define NS 1152
#define NO 10
#define ND 16
#define EPSV 1e-8f

#define RPB 64                 // s-rows per block (4 lanes per row, 256 threads)
#define SP (NS / RPB)          // 18 S-slices
#define PTHREADS 256

__global__ __launch_bounds__(PTHREADS)
void ar_pass(const float* __restrict__ u, const float* __restrict__ b_param,
             const float* __restrict__ vcum, float* __restrict__ ps,
             const int* __restrict__ n_iter_p, int r)
{
    if (r >= n_iter_p[0]) return;          // uniform no-op guard
    const int tid  = threadIdx.x;
    const int sl   = blockIdx.x;           // S-slice
    const int bg   = blockIdx.y;           // b*NG + g
    const int g    = bg & (NG - 1);
    const int d4   = tid & 3;              // float4 chunk of D
    const int row  = tid >> 2;             // 0..63
    const int s    = sl * RPB + row;
    const int wave = tid >> 6;
    const int lane = tid & 63;

    const float4* urow = (const float4*)u + ((size_t)bg * NS + s) * (NO * 4) + d4;
    const float4* vc   = (const float4*)vcum + (size_t)bg * (NO * 4) + d4;
    const float*  bp   = b_param + (size_t)g * (NS * NO) + (size_t)s * NO;

    // 10 independent 16B loads per lane (full row = 640B across 4 lanes)
    float4 uu[NO];
#pragma unroll
    for (int o = 0; o < NO; ++o) uu[o] = urow[o * 4];

    // logits = b_param + dot(u, vcum)  (vcum==0 on iteration 0)
    float bnew[NO];
#pragma unroll
    for (int o = 0; o < NO; ++o) {
        const float4 v4 = vc[o * 4];       // L1-hot (same 640B for whole block)
        float p = uu[o].x * v4.x + uu[o].y * v4.y + uu[o].z * v4.z + uu[o].w * v4.w;
        p += __shfl_xor(p, 1);
        p += __shfl_xor(p, 2);
        bnew[o] = bp[o] + p;
    }

    // in-register softmax over O (redundant per lane; BW-bound)
    float m = bnew[0];
#pragma unroll
    for (int o = 1; o < NO; ++o) m = fmaxf(m, bnew[o]);
    float ssum = 0.f;
#pragma unroll
    for (int o = 0; o < NO; ++o) { bnew[o] = __expf(bnew[o] - m); ssum += bnew[o]; }
    const float inv = 1.f / ssum;

#pragma unroll
    for (int o = 0; o < NO; ++o) {
        const float c = bnew[o] * inv;
        uu[o].x *= c; uu[o].y *= c; uu[o].z *= c; uu[o].w *= c;
    }

    // reduce the 16 rows of each wave (preserve d4 identity: masks 4..32)
#pragma unroll
    for (int o = 0; o < NO; ++o) {
#pragma unroll
        for (int mask = 4; mask <= 32; mask <<= 1) {
            uu[o].x += __shfl_xor(uu[o].x, mask);
            uu[o].y += __shfl_xor(uu[o].y, mask);
            uu[o].z += __shfl_xor(uu[o].z, mask);
            uu[o].w += __shfl_xor(uu[o].w, mask);
        }
    }

    __shared__ float4 red[PTHREADS / 64][NO][4];
    if (lane < 4) {
#pragma unroll
        for (int o = 0; o < NO; ++o) red[wave][o][lane] = uu[o];
    }
    __syncthreads();

    if (tid < NO * 4) {                    // 40 threads: (o, d-chunk)
        const int o = tid >> 2, dd = tid & 3;
        float4 a = red[0][o][dd];
#pragma unroll
        for (int w = 1; w < PTHREADS / 64; ++w) {
            const float4 t = red[w][o][dd];
            a.x += t.x; a.y += t.y; a.z += t.z; a.w += t.w;
        }
        ((float4*)ps)[(((size_t)bg * SP + sl) * NO + o) * 4 + dd] = a;
    }
}

__global__ __launch_bounds__(192)
void ar_squash(const float* __restrict__ ps, float* __restrict__ vcum,
               float* __restrict__ out, const int* __restrict__ n_iter_p, int r)
{
    const int n = n_iter_p[0];
    if (r >= n) return;
    const int tid = threadIdx.x;
    if (tid >= NO * ND) return;            // 160 active; 16-lane shfl groups intact
    const int bg = blockIdx.x;
    const int o = tid >> 4, d = tid & 15;

    const float* p = ps + ((size_t)bg * SP * NO + o) * ND + d;
    float s = 0.f;
#pragma unroll
    for (int sl = 0; sl < SP; ++sl) s += p[(size_t)sl * (NO * ND)];

    // squash: v = s * (|s|^2/(1+|s|^2)) / (|s|+eps), norm over the 16 d-lanes
    float q = s * s;
    q += __shfl_xor(q, 1); q += __shfl_xor(q, 2);
    q += __shfl_xor(q, 4); q += __shfl_xor(q, 8);
    const float len = sqrtf(q);
    const float f = (q / (1.f + q)) / (len + EPSV);
    const float v = s * f;

    vcum[(size_t)bg * (NO * ND) + tid] += v;          // running sum of v_j
    if (r == n - 1)
        atomicAdd(&out[(size_t)(bg >> 3) * (NO * ND) + tid], v);  // sum over g
}

extern "C" void kernel_launch(void* const* d_in, const int* in_sizes, int n_in,
                              void* d_out, int out_size, void* d_ws, size_t ws_size,
                              hipStream_t stream) {
    const float* u   = (const float*)d_in[0];
    const float* bp  = (const float*)d_in[1];
    const int*   nit = (const int*)d_in[2];
    float* out  = (float*)d_out;
    float* ps   = (float*)d_ws;                                   // [256][18][10][16] f32, 2.95 MB
    float* vcum = ps + (size_t)NB * NG * SP * NO * ND;            // [256][10][16] f32, 160 KB

    hipMemsetAsync(out, 0, (size_t)out_size * sizeof(float), stream);
    hipMemsetAsync(vcum, 0, (size_t)NB * NG * NO * ND * sizeof(float), stream);

    const dim3 pgrid(SP, NB * NG);
    for (int r = 0; r < 3; ++r) {          // n_iterations==3 per setup; device
        ar_pass<<<pgrid, PTHREADS, 0, stream>>>(u, bp, vcum, ps, nit, r);   // guards
        ar_squash<<<NB * NG, 192, 0, stream>>>(ps, vcum, out, nit, r);      // no-op extras
    }
}